// Round 1
// baseline (2708.648 us; speedup 1.0000x reference)
//
#include <hip/hip_runtime.h>

#define NU 160000
#define NM 60000
#define DD 64
#define NE 5000000
#define NL 200000

// w = 1/(l+1), l=0..3; layers all propagate layer-0 embeddings, so
// res = 1*x + (1/2 + 1/3 + 1/4) * agg = x + (13/12)*agg
#define COEF (13.0f / 12.0f)

__global__ void degree_kernel(const int* __restrict__ ef, const int* __restrict__ et,
                              float* __restrict__ deg_m, float* __restrict__ deg_u) {
    int i = blockIdx.x * blockDim.x + threadIdx.x;
    if (i < NE) {
        atomicAdd(&deg_m[ef[i]], 1.0f);
        atomicAdd(&deg_u[et[i]], 1.0f);
    }
}

__global__ void inv_kernel(float* __restrict__ deg, int n) {
    int i = blockIdx.x * blockDim.x + threadIdx.x;
    if (i < n) {
        float d = deg[i];
        deg[i] = (d > 0.0f) ? (1.0f / sqrtf(d)) : 0.0f;
    }
}

// one thread per (edge, dim); wave = one edge (64 dims)
__global__ void agg_kernel(const int* __restrict__ ef, const int* __restrict__ et,
                           const float* __restrict__ inv_m, const float* __restrict__ inv_u,
                           const float* __restrict__ x_u, const float* __restrict__ x_m,
                           float* __restrict__ res_u, float* __restrict__ res_m) {
    int tid = blockIdx.x * blockDim.x + threadIdx.x;
    int e = tid >> 6;
    int d = tid & 63;
    if (e < NE) {
        int f = ef[e];
        int t = et[e];
        float norm = inv_m[f] * inv_u[t] * COEF;
        // movie -> user
        atomicAdd(&res_u[t * DD + d], norm * x_m[f * DD + d]);
        // user -> movie
        atomicAdd(&res_m[f * DD + d], norm * x_u[t * DD + d]);
    }
}

__global__ void add_base_kernel(const float* __restrict__ xu, const float* __restrict__ xm,
                                float* __restrict__ ru, float* __restrict__ rm) {
    int i = blockIdx.x * blockDim.x + threadIdx.x;
    const int nu = NU * DD;
    const int nm = NM * DD;
    if (i < nu) {
        ru[i] += xu[i];
    } else if (i < nu + nm) {
        int j = i - nu;
        rm[j] += xm[j];
    }
}

// one wave per label edge; lane d holds dim d; wave-reduce the dot product
__global__ void score_kernel(const int* __restrict__ lm, const int* __restrict__ lu,
                             const float* __restrict__ ru, const float* __restrict__ rm,
                             float* __restrict__ scores) {
    int tid = blockIdx.x * blockDim.x + threadIdx.x;
    int l = tid >> 6;
    int d = tid & 63;
    if (l < NL) {
        int u = lu[l];
        int m = lm[l];
        float v = ru[u * DD + d] * rm[m * DD + d];
        #pragma unroll
        for (int off = 32; off >= 1; off >>= 1)
            v += __shfl_down(v, off, 64);
        if (d == 0) scores[l] = v;
    }
}

extern "C" void kernel_launch(void* const* d_in, const int* in_sizes, int n_in,
                              void* d_out, int out_size, void* d_ws, size_t ws_size,
                              hipStream_t stream) {
    const float* emb_user  = (const float*)d_in[0];
    const float* emb_movie = (const float*)d_in[1];
    // d_in[2], d_in[3] are node_id aranges (identity lookup) — unused
    const int* edge_from   = (const int*)d_in[4];
    const int* edge_to     = (const int*)d_in[5];
    const int* label_movie = (const int*)d_in[6];
    const int* label_user  = (const int*)d_in[7];

    float* out    = (float*)d_out;
    float* scores = out;                              // [NL]
    float* res_u  = out + NL;                         // [NU*DD]
    float* res_m  = out + NL + (size_t)NU * DD;       // [NM*DD]

    float* deg_u = (float*)d_ws;                      // [NU]
    float* deg_m = deg_u + NU;                        // [NM] (contiguous after deg_u)

    // zero-init accumulators (ws/out are poisoned 0xAA before every call)
    hipMemsetAsync(res_u, 0, (size_t)(NU + NM) * DD * sizeof(float), stream);
    hipMemsetAsync(deg_u, 0, (size_t)(NU + NM) * sizeof(float), stream);

    degree_kernel<<<(NE + 255) / 256, 256, 0, stream>>>(edge_from, edge_to, deg_m, deg_u);
    inv_kernel<<<(NU + NM + 255) / 256, 256, 0, stream>>>(deg_u, NU + NM);  // deg arrays contiguous

    agg_kernel<<<((size_t)NE * 64 + 255) / 256, 256, 0, stream>>>(
        edge_from, edge_to, deg_m /*inv_m*/, deg_u /*inv_u*/,
        emb_user, emb_movie, res_u, res_m);

    add_base_kernel<<<((NU + NM) * DD + 255) / 256, 256, 0, stream>>>(
        emb_user, emb_movie, res_u, res_m);

    score_kernel<<<((size_t)NL * 64 + 255) / 256, 256, 0, stream>>>(
        label_movie, label_user, res_u, res_m, scores);
}

// Round 2
// 2418.869 us; speedup vs baseline: 1.1198x; 1.1198x over previous
//
#include <hip/hip_runtime.h>

#define NU 160000
#define NM 60000
#define DD 64
#define NE 5000000
#define NL 200000

// w = 1/(l+1), l=0..3; all layers propagate layer-0 embeddings, so
// res = x + (1/2 + 1/3 + 1/4) * agg = x + (13/12)*agg
#define COEF (13.0f / 12.0f)

// ---------------- CSR path ----------------

__global__ void hist_kernel(const int* __restrict__ ef, const int* __restrict__ et,
                            int* __restrict__ deg_m, int* __restrict__ deg_u) {
    int i = blockIdx.x * blockDim.x + threadIdx.x;
    if (i < NE) {
        atomicAdd(&deg_m[ef[i]], 1);
        atomicAdd(&deg_u[et[i]], 1);
    }
}

// deg ints (contiguous deg_u,deg_m) -> inv floats (contiguous)
__global__ void inv_from_deg_kernel(const int* __restrict__ deg, float* __restrict__ inv, int n) {
    int i = blockIdx.x * blockDim.x + threadIdx.x;
    if (i < n) {
        int d = deg[i];
        inv[i] = (d > 0) ? rsqrtf((float)d) : 0.0f;
    }
}

// single-block exclusive scan, 256 threads x 4 elems/iter; row_ptr has n+1 entries
__global__ void scan_kernel(const int* __restrict__ deg, int* __restrict__ row_ptr, int n) {
    __shared__ int buf[256];
    __shared__ int carry;
    int tid = threadIdx.x;
    if (tid == 0) carry = 0;
    __syncthreads();
    for (int base = 0; base < n; base += 1024) {
        int idx = base + tid * 4;
        int v0 = (idx + 0 < n) ? deg[idx + 0] : 0;
        int v1 = (idx + 1 < n) ? deg[idx + 1] : 0;
        int v2 = (idx + 2 < n) ? deg[idx + 2] : 0;
        int v3 = (idx + 3 < n) ? deg[idx + 3] : 0;
        int s = v0 + v1 + v2 + v3;
        buf[tid] = s;
        __syncthreads();
        for (int off = 1; off < 256; off <<= 1) {
            int t = (tid >= off) ? buf[tid - off] : 0;
            __syncthreads();
            buf[tid] += t;
            __syncthreads();
        }
        int excl = buf[tid] - s;       // exclusive prefix of this thread's group
        int p = carry + excl;
        if (idx + 0 < n) { row_ptr[idx + 0] = p; p += v0; }
        if (idx + 1 < n) { row_ptr[idx + 1] = p; p += v1; }
        if (idx + 2 < n) { row_ptr[idx + 2] = p; p += v2; }
        if (idx + 3 < n) { row_ptr[idx + 3] = p; p += v3; }
        __syncthreads();
        if (tid == 0) carry += buf[255];   // chunk total
        __syncthreads();
    }
    if (tid == 0) row_ptr[n] = carry;
}

__global__ void copy_int_kernel(const int* __restrict__ src, int* __restrict__ dst, int n) {
    int i = blockIdx.x * blockDim.x + threadIdx.x;
    if (i < n) dst[i] = src[i];
}

__global__ void scatter_kernel(const int* __restrict__ ef, const int* __restrict__ et,
                               int* __restrict__ cur_u, int* __restrict__ cur_m,
                               int* __restrict__ pay_u, int* __restrict__ pay_m) {
    int e = blockIdx.x * blockDim.x + threadIdx.x;
    if (e < NE) {
        int f = ef[e];
        int t = et[e];
        pay_u[atomicAdd(&cur_u[t], 1)] = f;   // user t's neighbor movie f
        pay_m[atomicAdd(&cur_m[f], 1)] = t;   // movie f's neighbor user t
    }
}

// one wave per destination node; lane = dim. res = base + COEF*inv_dst * sum(inv_src[f]*x_src[f,:])
__global__ void gather_kernel(const int* __restrict__ rp, const int* __restrict__ pay,
                              const float* __restrict__ inv_dst, const float* __restrict__ inv_src,
                              const float* __restrict__ x_src, const float* __restrict__ x_dst,
                              float* __restrict__ res, int n) {
    int tid = blockIdx.x * blockDim.x + threadIdx.x;
    int node = tid >> 6;
    int lane = threadIdx.x & 63;
    if (node >= n) return;
    int start = rp[node];
    int end   = rp[node + 1];
    float acc = 0.0f;
    for (int i = start; i < end; i += 64) {
        int nid = (i + lane < end) ? pay[i + lane] : 0;
        int cnt = min(end - i, 64);
        for (int j = 0; j < cnt; j++) {
            int f = __shfl(nid, j, 64);
            acc += inv_src[f] * x_src[f * DD + lane];
        }
    }
    int o = node * DD + lane;
    res[o] = x_dst[o] + COEF * inv_dst[node] * acc;
}

// one wave per label edge; lane d holds dim d; wave-reduce the dot product
__global__ void score_kernel(const int* __restrict__ lm, const int* __restrict__ lu,
                             const float* __restrict__ ru, const float* __restrict__ rm,
                             float* __restrict__ scores) {
    int tid = blockIdx.x * blockDim.x + threadIdx.x;
    int l = tid >> 6;
    int d = threadIdx.x & 63;
    if (l < NL) {
        int u = lu[l];
        int m = lm[l];
        float v = ru[u * DD + d] * rm[m * DD + d];
        #pragma unroll
        for (int off = 32; off >= 1; off >>= 1)
            v += __shfl_down(v, off, 64);
        if (d == 0) scores[l] = v;
    }
}

// ---------------- fallback (round-1 atomic path) ----------------

__global__ void degree_kernel_f(const int* __restrict__ ef, const int* __restrict__ et,
                                float* __restrict__ deg_m, float* __restrict__ deg_u) {
    int i = blockIdx.x * blockDim.x + threadIdx.x;
    if (i < NE) {
        atomicAdd(&deg_m[ef[i]], 1.0f);
        atomicAdd(&deg_u[et[i]], 1.0f);
    }
}

__global__ void inv_kernel_f(float* __restrict__ deg, int n) {
    int i = blockIdx.x * blockDim.x + threadIdx.x;
    if (i < n) {
        float d = deg[i];
        deg[i] = (d > 0.0f) ? (1.0f / sqrtf(d)) : 0.0f;
    }
}

__global__ void agg_kernel_f(const int* __restrict__ ef, const int* __restrict__ et,
                             const float* __restrict__ inv_m, const float* __restrict__ inv_u,
                             const float* __restrict__ x_u, const float* __restrict__ x_m,
                             float* __restrict__ res_u, float* __restrict__ res_m) {
    int tid = blockIdx.x * blockDim.x + threadIdx.x;
    int e = tid >> 6;
    int d = tid & 63;
    if (e < NE) {
        int f = ef[e];
        int t = et[e];
        float norm = inv_m[f] * inv_u[t] * COEF;
        atomicAdd(&res_u[t * DD + d], norm * x_m[f * DD + d]);
        atomicAdd(&res_m[f * DD + d], norm * x_u[t * DD + d]);
    }
}

__global__ void add_base_kernel_f(const float* __restrict__ xu, const float* __restrict__ xm,
                                  float* __restrict__ ru, float* __restrict__ rm) {
    int i = blockIdx.x * blockDim.x + threadIdx.x;
    const int nu = NU * DD;
    const int nm = NM * DD;
    if (i < nu) {
        ru[i] += xu[i];
    } else if (i < nu + nm) {
        int j = i - nu;
        rm[j] += xm[j];
    }
}

// ---------------- launch ----------------

extern "C" void kernel_launch(void* const* d_in, const int* in_sizes, int n_in,
                              void* d_out, int out_size, void* d_ws, size_t ws_size,
                              hipStream_t stream) {
    const float* emb_user  = (const float*)d_in[0];
    const float* emb_movie = (const float*)d_in[1];
    const int* edge_from   = (const int*)d_in[4];
    const int* edge_to     = (const int*)d_in[5];
    const int* label_movie = (const int*)d_in[6];
    const int* label_user  = (const int*)d_in[7];

    float* out    = (float*)d_out;
    float* scores = out;                              // [NL]
    float* res_u  = out + NL;                         // [NU*DD]
    float* res_m  = out + NL + (size_t)NU * DD;       // [NM*DD]

    // ws layout (CSR path)
    int*   deg_u = (int*)d_ws;                        // NU
    int*   deg_m = deg_u + NU;                        // NM  (contiguous after deg_u)
    int*   rp_u  = deg_m + NM;                        // NU+1
    int*   rp_m  = rp_u + NU + 1;                     // NM+1
    int*   cur_u = rp_m + NM + 1;                     // NU
    int*   cur_m = cur_u + NU;                        // NM
    float* inv_u = (float*)(cur_m + NM);              // NU
    float* inv_m = inv_u + NU;                        // NM  (contiguous after inv_u)
    int*   pay_u = (int*)(inv_m + NM);                // NE
    int*   pay_m = pay_u + NE;                        // NE

    size_t needed = ((size_t)(NU + NM) * 4 + 2 + 2 * (size_t)NE) * sizeof(int);

    if (ws_size >= needed) {
        // ---- CSR path ----
        hipMemsetAsync(deg_u, 0, (size_t)(NU + NM) * sizeof(int), stream);

        hist_kernel<<<(NE + 255) / 256, 256, 0, stream>>>(edge_from, edge_to, deg_m, deg_u);
        inv_from_deg_kernel<<<(NU + NM + 255) / 256, 256, 0, stream>>>(deg_u, inv_u, NU + NM);

        scan_kernel<<<1, 256, 0, stream>>>(deg_u, rp_u, NU);
        scan_kernel<<<1, 256, 0, stream>>>(deg_m, rp_m, NM);

        copy_int_kernel<<<(NU + 255) / 256, 256, 0, stream>>>(rp_u, cur_u, NU);
        copy_int_kernel<<<(NM + 255) / 256, 256, 0, stream>>>(rp_m, cur_m, NM);

        scatter_kernel<<<(NE + 255) / 256, 256, 0, stream>>>(
            edge_from, edge_to, cur_u, cur_m, pay_u, pay_m);

        // users: gather movie rows
        gather_kernel<<<((size_t)NU * 64 + 255) / 256, 256, 0, stream>>>(
            rp_u, pay_u, inv_u, inv_m, emb_movie, emb_user, res_u, NU);
        // movies: gather user rows
        gather_kernel<<<((size_t)NM * 64 + 255) / 256, 256, 0, stream>>>(
            rp_m, pay_m, inv_m, inv_u, emb_user, emb_movie, res_m, NM);
    } else {
        // ---- fallback: atomic path ----
        float* fdeg_u = (float*)d_ws;
        float* fdeg_m = fdeg_u + NU;
        hipMemsetAsync(res_u, 0, (size_t)(NU + NM) * DD * sizeof(float), stream);
        hipMemsetAsync(fdeg_u, 0, (size_t)(NU + NM) * sizeof(float), stream);
        degree_kernel_f<<<(NE + 255) / 256, 256, 0, stream>>>(edge_from, edge_to, fdeg_m, fdeg_u);
        inv_kernel_f<<<(NU + NM + 255) / 256, 256, 0, stream>>>(fdeg_u, NU + NM);
        agg_kernel_f<<<((size_t)NE * 64 + 255) / 256, 256, 0, stream>>>(
            edge_from, edge_to, fdeg_m, fdeg_u, emb_user, emb_movie, res_u, res_m);
        add_base_kernel_f<<<((NU + NM) * DD + 255) / 256, 256, 0, stream>>>(
            emb_user, emb_movie, res_u, res_m);
    }

    score_kernel<<<((size_t)NL * 64 + 255) / 256, 256, 0, stream>>>(
        label_movie, label_user, res_u, res_m, scores);
}

// Round 3
// 1747.294 us; speedup vs baseline: 1.5502x; 1.3844x over previous
//
#include <hip/hip_runtime.h>

#define NU 160000
#define NM 60000
#define DD 64
#define NE 5000000
#define NL 200000

// w = 1/(l+1), l=0..3; all layers propagate layer-0 embeddings, so
// res = x + (1/2 + 1/3 + 1/4) * agg = x + (13/12)*agg
#define COEF (13.0f / 12.0f)

#define CHUNK 1024                     // scan chunk = 256 threads x 4
#define NCH_U ((NU + CHUNK - 1) / CHUNK)   // 157
#define NCH_M ((NM + CHUNK - 1) / CHUNK)   // 59

// ---------------- histogram ----------------

__global__ void hist_kernel(const int* __restrict__ ef, const int* __restrict__ et,
                            int* __restrict__ deg_m, int* __restrict__ deg_u) {
    int i = blockIdx.x * blockDim.x + threadIdx.x;
    if (i < NE) {
        atomicAdd(&deg_m[ef[i]], 1);
        atomicAdd(&deg_u[et[i]], 1);
    }
}

__global__ void inv_from_deg_kernel(const int* __restrict__ deg, float* __restrict__ inv, int n) {
    int i = blockIdx.x * blockDim.x + threadIdx.x;
    if (i < n) {
        int d = deg[i];
        inv[i] = (d > 0) ? rsqrtf((float)d) : 0.0f;
    }
}

// ---------------- 3-phase scan ----------------

// phase A: per-chunk sums
__global__ void chunk_sum_kernel(const int* __restrict__ deg, int* __restrict__ partial, int n) {
    __shared__ int buf[256];
    int tid = threadIdx.x;
    int idx = blockIdx.x * CHUNK + tid * 4;
    int s = 0;
    #pragma unroll
    for (int k = 0; k < 4; k++)
        if (idx + k < n) s += deg[idx + k];
    buf[tid] = s;
    __syncthreads();
    for (int off = 128; off >= 1; off >>= 1) {
        if (tid < off) buf[tid] += buf[tid + off];
        __syncthreads();
    }
    if (tid == 0) partial[blockIdx.x] = buf[0];
}

// phase B: single-block exclusive scan of partials (n <= 1024); out[n] = total
__global__ void scan_small_kernel(const int* __restrict__ in, int* __restrict__ out, int n) {
    __shared__ int buf[256];
    int tid = threadIdx.x;
    int idx = tid * 4;
    int v0 = (idx + 0 < n) ? in[idx + 0] : 0;
    int v1 = (idx + 1 < n) ? in[idx + 1] : 0;
    int v2 = (idx + 2 < n) ? in[idx + 2] : 0;
    int v3 = (idx + 3 < n) ? in[idx + 3] : 0;
    int s = v0 + v1 + v2 + v3;
    buf[tid] = s;
    __syncthreads();
    for (int off = 1; off < 256; off <<= 1) {
        int t = (tid >= off) ? buf[tid - off] : 0;
        __syncthreads();
        buf[tid] += t;
        __syncthreads();
    }
    int p = buf[tid] - s;   // exclusive prefix
    if (idx + 0 < n) { out[idx + 0] = p; p += v0; }
    if (idx + 1 < n) { out[idx + 1] = p; p += v1; }
    if (idx + 2 < n) { out[idx + 2] = p; p += v2; }
    if (idx + 3 < n) { out[idx + 3] = p; p += v3; }
    if (tid == 255) out[n] = buf[255];
}

// phase C: per-chunk exclusive scan + chunk offset; writes row_ptr AND cursor copy
__global__ void chunk_scan_kernel(const int* __restrict__ deg, const int* __restrict__ ppart,
                                  int* __restrict__ row_ptr, int* __restrict__ cur,
                                  int n, int nchunks) {
    __shared__ int buf[256];
    int tid = threadIdx.x;
    int idx = blockIdx.x * CHUNK + tid * 4;
    int v0 = (idx + 0 < n) ? deg[idx + 0] : 0;
    int v1 = (idx + 1 < n) ? deg[idx + 1] : 0;
    int v2 = (idx + 2 < n) ? deg[idx + 2] : 0;
    int v3 = (idx + 3 < n) ? deg[idx + 3] : 0;
    int s = v0 + v1 + v2 + v3;
    buf[tid] = s;
    __syncthreads();
    for (int off = 1; off < 256; off <<= 1) {
        int t = (tid >= off) ? buf[tid - off] : 0;
        __syncthreads();
        buf[tid] += t;
        __syncthreads();
    }
    int p = ppart[blockIdx.x] + buf[tid] - s;
    if (idx + 0 < n) { row_ptr[idx + 0] = p; cur[idx + 0] = p; p += v0; }
    if (idx + 1 < n) { row_ptr[idx + 1] = p; cur[idx + 1] = p; p += v1; }
    if (idx + 2 < n) { row_ptr[idx + 2] = p; cur[idx + 2] = p; p += v2; }
    if (idx + 3 < n) { row_ptr[idx + 3] = p; cur[idx + 3] = p; p += v3; }
    if (blockIdx.x == 0 && tid == 0) row_ptr[n] = ppart[nchunks];
}

// ---------------- scatter (ILP x8) ----------------

#define SCK 8  // edges per thread; NE % SCK == 0

__global__ void scatter_kernel(const int* __restrict__ ef, const int* __restrict__ et,
                               int* __restrict__ cur_u, int* __restrict__ cur_m,
                               int* __restrict__ pay_u, int* __restrict__ pay_m) {
    int tid = blockIdx.x * blockDim.x + threadIdx.x;
    int base = tid * SCK;
    if (base >= NE) return;
    const int4* ef4 = (const int4*)(ef + base);
    const int4* et4 = (const int4*)(et + base);
    int4 fa = ef4[0], fb = ef4[1];
    int4 ta = et4[0], tb = et4[1];
    int f[SCK] = {fa.x, fa.y, fa.z, fa.w, fb.x, fb.y, fb.z, fb.w};
    int t[SCK] = {ta.x, ta.y, ta.z, ta.w, tb.x, tb.y, tb.z, tb.w};
    int su[SCK], sm[SCK];
    #pragma unroll
    for (int k = 0; k < SCK; k++) su[k] = atomicAdd(&cur_u[t[k]], 1);
    #pragma unroll
    for (int k = 0; k < SCK; k++) sm[k] = atomicAdd(&cur_m[f[k]], 1);
    #pragma unroll
    for (int k = 0; k < SCK; k++) pay_u[su[k]] = f[k];
    #pragma unroll
    for (int k = 0; k < SCK; k++) pay_m[sm[k]] = t[k];
}

// ---------------- gather ----------------

// one wave per destination node; lane = dim. res = base + COEF*inv_dst * sum(inv_src[f]*x_src[f,:])
__global__ void gather_kernel(const int* __restrict__ rp, const int* __restrict__ pay,
                              const float* __restrict__ inv_dst, const float* __restrict__ inv_src,
                              const float* __restrict__ x_src, const float* __restrict__ x_dst,
                              float* __restrict__ res, int n) {
    int tid = blockIdx.x * blockDim.x + threadIdx.x;
    int node = tid >> 6;
    int lane = threadIdx.x & 63;
    if (node >= n) return;
    int start = rp[node];
    int end   = rp[node + 1];
    float acc = 0.0f;
    for (int i = start; i < end; i += 64) {
        int cnt = min(end - i, 64);
        int nid = (lane < cnt) ? pay[i + lane] : 0;
        int j = 0;
        for (; j + 4 <= cnt; j += 4) {
            int f0 = __shfl(nid, j + 0, 64);
            int f1 = __shfl(nid, j + 1, 64);
            int f2 = __shfl(nid, j + 2, 64);
            int f3 = __shfl(nid, j + 3, 64);
            float w0 = inv_src[f0], w1 = inv_src[f1], w2 = inv_src[f2], w3 = inv_src[f3];
            float a0 = x_src[f0 * DD + lane];
            float a1 = x_src[f1 * DD + lane];
            float a2 = x_src[f2 * DD + lane];
            float a3 = x_src[f3 * DD + lane];
            acc += w0 * a0 + w1 * a1 + w2 * a2 + w3 * a3;
        }
        for (; j < cnt; j++) {
            int f0 = __shfl(nid, j, 64);
            acc += inv_src[f0] * x_src[f0 * DD + lane];
        }
    }
    int o = node * DD + lane;
    res[o] = x_dst[o] + COEF * inv_dst[node] * acc;
}

// ---------------- score ----------------

__global__ void score_kernel(const int* __restrict__ lm, const int* __restrict__ lu,
                             const float* __restrict__ ru, const float* __restrict__ rm,
                             float* __restrict__ scores) {
    int tid = blockIdx.x * blockDim.x + threadIdx.x;
    int l = tid >> 6;
    int d = threadIdx.x & 63;
    if (l < NL) {
        int u = lu[l];
        int m = lm[l];
        float v = ru[u * DD + d] * rm[m * DD + d];
        #pragma unroll
        for (int off = 32; off >= 1; off >>= 1)
            v += __shfl_down(v, off, 64);
        if (d == 0) scores[l] = v;
    }
}

// ---------------- fallback (atomic path) ----------------

__global__ void degree_kernel_f(const int* __restrict__ ef, const int* __restrict__ et,
                                float* __restrict__ deg_m, float* __restrict__ deg_u) {
    int i = blockIdx.x * blockDim.x + threadIdx.x;
    if (i < NE) {
        atomicAdd(&deg_m[ef[i]], 1.0f);
        atomicAdd(&deg_u[et[i]], 1.0f);
    }
}

__global__ void inv_kernel_f(float* __restrict__ deg, int n) {
    int i = blockIdx.x * blockDim.x + threadIdx.x;
    if (i < n) {
        float d = deg[i];
        deg[i] = (d > 0.0f) ? (1.0f / sqrtf(d)) : 0.0f;
    }
}

__global__ void agg_kernel_f(const int* __restrict__ ef, const int* __restrict__ et,
                             const float* __restrict__ inv_m, const float* __restrict__ inv_u,
                             const float* __restrict__ x_u, const float* __restrict__ x_m,
                             float* __restrict__ res_u, float* __restrict__ res_m) {
    int tid = blockIdx.x * blockDim.x + threadIdx.x;
    int e = tid >> 6;
    int d = tid & 63;
    if (e < NE) {
        int f = ef[e];
        int t = et[e];
        float norm = inv_m[f] * inv_u[t] * COEF;
        atomicAdd(&res_u[t * DD + d], norm * x_m[f * DD + d]);
        atomicAdd(&res_m[f * DD + d], norm * x_u[t * DD + d]);
    }
}

__global__ void add_base_kernel_f(const float* __restrict__ xu, const float* __restrict__ xm,
                                  float* __restrict__ ru, float* __restrict__ rm) {
    int i = blockIdx.x * blockDim.x + threadIdx.x;
    const int nu = NU * DD;
    const int nm = NM * DD;
    if (i < nu) {
        ru[i] += xu[i];
    } else if (i < nu + nm) {
        int j = i - nu;
        rm[j] += xm[j];
    }
}

// ---------------- launch ----------------

extern "C" void kernel_launch(void* const* d_in, const int* in_sizes, int n_in,
                              void* d_out, int out_size, void* d_ws, size_t ws_size,
                              hipStream_t stream) {
    const float* emb_user  = (const float*)d_in[0];
    const float* emb_movie = (const float*)d_in[1];
    const int* edge_from   = (const int*)d_in[4];
    const int* edge_to     = (const int*)d_in[5];
    const int* label_movie = (const int*)d_in[6];
    const int* label_user  = (const int*)d_in[7];

    float* out    = (float*)d_out;
    float* scores = out;                              // [NL]
    float* res_u  = out + NL;                         // [NU*DD]
    float* res_m  = out + NL + (size_t)NU * DD;       // [NM*DD]

    // ws layout (CSR path)
    int*   deg_u  = (int*)d_ws;                       // NU
    int*   deg_m  = deg_u + NU;                       // NM  (contiguous after deg_u)
    int*   rp_u   = deg_m + NM;                       // NU+1
    int*   rp_m   = rp_u + NU + 1;                    // NM+1
    int*   cur_u  = rp_m + NM + 1;                    // NU
    int*   cur_m  = cur_u + NU;                       // NM
    float* inv_u  = (float*)(cur_m + NM);             // NU
    float* inv_m  = inv_u + NU;                       // NM  (contiguous after inv_u)
    int*   pay_u  = (int*)(inv_m + NM);               // NE
    int*   pay_m  = pay_u + NE;                       // NE
    int*   part_u = pay_m + NE;                       // NCH_U+1
    int*   part_m = part_u + NCH_U + 1;               // NCH_M+1

    size_t needed = ((size_t)(NU + NM) * 4 + 2 + 2 * (size_t)NE + NCH_U + NCH_M + 2)
                    * sizeof(int);

    if (ws_size >= needed) {
        // ---- CSR path ----
        hipMemsetAsync(deg_u, 0, (size_t)(NU + NM) * sizeof(int), stream);

        hist_kernel<<<(NE + 255) / 256, 256, 0, stream>>>(edge_from, edge_to, deg_m, deg_u);
        inv_from_deg_kernel<<<(NU + NM + 255) / 256, 256, 0, stream>>>(deg_u, inv_u, NU + NM);

        // 3-phase scans (users and movies)
        chunk_sum_kernel<<<NCH_U, 256, 0, stream>>>(deg_u, part_u, NU);
        chunk_sum_kernel<<<NCH_M, 256, 0, stream>>>(deg_m, part_m, NM);
        scan_small_kernel<<<1, 256, 0, stream>>>(part_u, part_u, NCH_U);
        scan_small_kernel<<<1, 256, 0, stream>>>(part_m, part_m, NCH_M);
        chunk_scan_kernel<<<NCH_U, 256, 0, stream>>>(deg_u, part_u, rp_u, cur_u, NU, NCH_U);
        chunk_scan_kernel<<<NCH_M, 256, 0, stream>>>(deg_m, part_m, rp_m, cur_m, NM, NCH_M);

        scatter_kernel<<<(NE / SCK + 255) / 256, 256, 0, stream>>>(
            edge_from, edge_to, cur_u, cur_m, pay_u, pay_m);

        // users: gather movie rows
        gather_kernel<<<((size_t)NU * 64 + 255) / 256, 256, 0, stream>>>(
            rp_u, pay_u, inv_u, inv_m, emb_movie, emb_user, res_u, NU);
        // movies: gather user rows
        gather_kernel<<<((size_t)NM * 64 + 255) / 256, 256, 0, stream>>>(
            rp_m, pay_m, inv_m, inv_u, emb_user, emb_movie, res_m, NM);
    } else {
        // ---- fallback: atomic path ----
        float* fdeg_u = (float*)d_ws;
        float* fdeg_m = fdeg_u + NU;
        hipMemsetAsync(res_u, 0, (size_t)(NU + NM) * DD * sizeof(float), stream);
        hipMemsetAsync(fdeg_u, 0, (size_t)(NU + NM) * sizeof(float), stream);
        degree_kernel_f<<<(NE + 255) / 256, 256, 0, stream>>>(edge_from, edge_to, fdeg_m, fdeg_u);
        inv_kernel_f<<<(NU + NM + 255) / 256, 256, 0, stream>>>(fdeg_u, NU + NM);
        agg_kernel_f<<<((size_t)NE * 64 + 255) / 256, 256, 0, stream>>>(
            edge_from, edge_to, fdeg_m, fdeg_u, emb_user, emb_movie, res_u, res_m);
        add_base_kernel_f<<<((NU + NM) * DD + 255) / 256, 256, 0, stream>>>(
            emb_user, emb_movie, res_u, res_m);
    }

    score_kernel<<<((size_t)NL * 64 + 255) / 256, 256, 0, stream>>>(
        label_movie, label_user, res_u, res_m, scores);
}

// Round 4
// 1462.420 us; speedup vs baseline: 1.8522x; 1.1948x over previous
//
#include <hip/hip_runtime.h>

#define NU 160000
#define NM 60000
#define DD 64
#define NE 5000000
#define NL 200000

// w = 1/(l+1), l=0..3; all layers propagate layer-0 embeddings, so
// res = x + (1/2 + 1/3 + 1/4) * agg = x + (13/12)*agg
#define COEF (13.0f / 12.0f)

#define CHUNK 1024                         // scan chunk = 256 threads x 4
#define NCH_U ((NU + CHUNK - 1) / CHUNK)   // 157
#define NCH_M ((NM + CHUNK - 1) / CHUNK)   // 59

#define NB 128          // max coarse buckets
#define SHIFT_U 11      // 2048 users/bucket -> 79 buckets
#define SHIFT_M 9       // 512 movies/bucket -> 118 buckets

// ---------------- histogram (degrees + coarse bucket counts) ----------------

__global__ void hist_kernel(const int* __restrict__ ef, const int* __restrict__ et,
                            int* __restrict__ deg_m, int* __restrict__ deg_u,
                            int* __restrict__ gbh_u, int* __restrict__ gbh_m) {
    __shared__ int bhu[NB], bhm[NB];
    int tid = threadIdx.x;
    if (tid < NB) { bhu[tid] = 0; bhm[tid] = 0; }
    __syncthreads();
    int base = (blockIdx.x * 256 + tid) * 4;
    if (base < NE) {   // NE % 4 == 0 -> all-or-none
        int4 f4 = *(const int4*)(ef + base);
        int4 t4 = *(const int4*)(et + base);
        int fs[4] = {f4.x, f4.y, f4.z, f4.w};
        int ts[4] = {t4.x, t4.y, t4.z, t4.w};
        #pragma unroll
        for (int q = 0; q < 4; q++) {
            atomicAdd(&deg_m[fs[q]], 1);
            atomicAdd(&deg_u[ts[q]], 1);
            atomicAdd(&bhm[fs[q] >> SHIFT_M], 1);
            atomicAdd(&bhu[ts[q] >> SHIFT_U], 1);
        }
    }
    __syncthreads();
    if (tid < NB) {
        if (bhu[tid]) atomicAdd(&gbh_u[tid], bhu[tid]);
        if (bhm[tid]) atomicAdd(&gbh_m[tid], bhm[tid]);
    }
}

__global__ void inv_from_deg_kernel(const int* __restrict__ deg, float* __restrict__ inv, int n) {
    int i = blockIdx.x * blockDim.x + threadIdx.x;
    if (i < n) {
        int d = deg[i];
        inv[i] = (d > 0) ? rsqrtf((float)d) : 0.0f;
    }
}

// ---------------- scans ----------------

__global__ void chunk_sum_kernel(const int* __restrict__ deg, int* __restrict__ partial, int n) {
    __shared__ int buf[256];
    int tid = threadIdx.x;
    int idx = blockIdx.x * CHUNK + tid * 4;
    int s = 0;
    #pragma unroll
    for (int k = 0; k < 4; k++)
        if (idx + k < n) s += deg[idx + k];
    buf[tid] = s;
    __syncthreads();
    for (int off = 128; off >= 1; off >>= 1) {
        if (tid < off) buf[tid] += buf[tid + off];
        __syncthreads();
    }
    if (tid == 0) partial[blockIdx.x] = buf[0];
}

// single-block exclusive scan (n <= 1024); out[n] = total; optional cursor copy
__global__ void scan_small_kernel(const int* __restrict__ in, int* __restrict__ out,
                                  int* __restrict__ cur, int n) {
    __shared__ int buf[256];
    int tid = threadIdx.x;
    int idx = tid * 4;
    int v0 = (idx + 0 < n) ? in[idx + 0] : 0;
    int v1 = (idx + 1 < n) ? in[idx + 1] : 0;
    int v2 = (idx + 2 < n) ? in[idx + 2] : 0;
    int v3 = (idx + 3 < n) ? in[idx + 3] : 0;
    int s = v0 + v1 + v2 + v3;
    buf[tid] = s;
    __syncthreads();
    for (int off = 1; off < 256; off <<= 1) {
        int t = (tid >= off) ? buf[tid - off] : 0;
        __syncthreads();
        buf[tid] += t;
        __syncthreads();
    }
    int p = buf[tid] - s;   // exclusive prefix
    if (idx + 0 < n) { out[idx + 0] = p; if (cur) cur[idx + 0] = p; p += v0; }
    if (idx + 1 < n) { out[idx + 1] = p; if (cur) cur[idx + 1] = p; p += v1; }
    if (idx + 2 < n) { out[idx + 2] = p; if (cur) cur[idx + 2] = p; p += v2; }
    if (idx + 3 < n) { out[idx + 3] = p; if (cur) cur[idx + 3] = p; p += v3; }
    if (tid == 255) out[n] = buf[255];
}

// per-chunk exclusive scan + chunk offset; writes row_ptr AND cursor copy
__global__ void chunk_scan_kernel(const int* __restrict__ deg, const int* __restrict__ ppart,
                                  int* __restrict__ row_ptr, int* __restrict__ cur,
                                  int n, int nchunks) {
    __shared__ int buf[256];
    int tid = threadIdx.x;
    int idx = blockIdx.x * CHUNK + tid * 4;
    int v0 = (idx + 0 < n) ? deg[idx + 0] : 0;
    int v1 = (idx + 1 < n) ? deg[idx + 1] : 0;
    int v2 = (idx + 2 < n) ? deg[idx + 2] : 0;
    int v3 = (idx + 3 < n) ? deg[idx + 3] : 0;
    int s = v0 + v1 + v2 + v3;
    buf[tid] = s;
    __syncthreads();
    for (int off = 1; off < 256; off <<= 1) {
        int t = (tid >= off) ? buf[tid - off] : 0;
        __syncthreads();
        buf[tid] += t;
        __syncthreads();
    }
    int p = ppart[blockIdx.x] + buf[tid] - s;
    if (idx + 0 < n) { row_ptr[idx + 0] = p; cur[idx + 0] = p; p += v0; }
    if (idx + 1 < n) { row_ptr[idx + 1] = p; cur[idx + 1] = p; p += v1; }
    if (idx + 2 < n) { row_ptr[idx + 2] = p; cur[idx + 2] = p; p += v2; }
    if (idx + 3 < n) { row_ptr[idx + 3] = p; cur[idx + 3] = p; p += v3; }
    if (blockIdx.x == 0 && tid == 0) row_ptr[n] = ppart[nchunks];
}

// ---------------- coarse partition (bucket-grouped staging) ----------------

#define PEC 16   // edges per thread; 4096 per block

__global__ void partition_kernel(const int* __restrict__ key, const int* __restrict__ val,
                                 int* __restrict__ bcur, int2* __restrict__ stage, int shift) {
    __shared__ int lh[NB];
    __shared__ int lbase[NB];
    int tid = threadIdx.x;
    if (tid < NB) lh[tid] = 0;
    __syncthreads();
    int base = (blockIdx.x * 256 + tid) * PEC;
    int k_[PEC], v_[PEC], br_[PEC];
    bool act = base < NE;   // NE % 16 == 0 -> all-or-none
    if (act) {
        const int4* k4 = (const int4*)(key + base);
        const int4* v4 = (const int4*)(val + base);
        #pragma unroll
        for (int q = 0; q < PEC / 4; q++) {
            int4 kk = k4[q]; int4 vv = v4[q];
            k_[q * 4 + 0] = kk.x; k_[q * 4 + 1] = kk.y; k_[q * 4 + 2] = kk.z; k_[q * 4 + 3] = kk.w;
            v_[q * 4 + 0] = vv.x; v_[q * 4 + 1] = vv.y; v_[q * 4 + 2] = vv.z; v_[q * 4 + 3] = vv.w;
        }
        #pragma unroll
        for (int q = 0; q < PEC; q++) {
            int b = k_[q] >> shift;
            int r = atomicAdd(&lh[b], 1);       // rank within (block,bucket), < 4096
            br_[q] = (b << 13) | r;
        }
    }
    __syncthreads();
    if (tid < NB) lbase[tid] = lh[tid] ? atomicAdd(&bcur[tid], lh[tid]) : 0;
    __syncthreads();
    if (act) {
        #pragma unroll
        for (int q = 0; q < PEC; q++) {
            int b = br_[q] >> 13;
            int r = br_[q] & 8191;
            stage[lbase[b] + r] = make_int2(k_[q], v_[q]);
        }
    }
}

// ---------------- fine scatter (bucket-local destinations) ----------------

#define FEC 8

__global__ void fine_kernel(const int2* __restrict__ stage, int* __restrict__ cur,
                            int* __restrict__ pay) {
    int base = (blockIdx.x * 256 + threadIdx.x) * FEC;
    if (base >= NE) return;   // NE % 8 == 0
    const int4* s4 = (const int4*)(stage + base);
    int2 p[FEC];
    #pragma unroll
    for (int q = 0; q < FEC / 2; q++) {
        int4 w = s4[q];
        p[2 * q + 0] = make_int2(w.x, w.y);
        p[2 * q + 1] = make_int2(w.z, w.w);
    }
    int s[FEC];
    #pragma unroll
    for (int q = 0; q < FEC; q++) s[q] = atomicAdd(&cur[p[q].x], 1);
    #pragma unroll
    for (int q = 0; q < FEC; q++) pay[s[q]] = p[q].y;
}

// ---------------- gather ----------------

__global__ void gather_kernel(const int* __restrict__ rp, const int* __restrict__ pay,
                              const float* __restrict__ inv_dst, const float* __restrict__ inv_src,
                              const float* __restrict__ x_src, const float* __restrict__ x_dst,
                              float* __restrict__ res, int n) {
    int tid = blockIdx.x * blockDim.x + threadIdx.x;
    int node = tid >> 6;
    int lane = threadIdx.x & 63;
    if (node >= n) return;
    int start = rp[node];
    int end   = rp[node + 1];
    float acc = 0.0f;
    for (int i = start; i < end; i += 64) {
        int cnt = min(end - i, 64);
        int nid = (lane < cnt) ? pay[i + lane] : 0;
        int j = 0;
        for (; j + 4 <= cnt; j += 4) {
            int f0 = __shfl(nid, j + 0, 64);
            int f1 = __shfl(nid, j + 1, 64);
            int f2 = __shfl(nid, j + 2, 64);
            int f3 = __shfl(nid, j + 3, 64);
            float w0 = inv_src[f0], w1 = inv_src[f1], w2 = inv_src[f2], w3 = inv_src[f3];
            float a0 = x_src[f0 * DD + lane];
            float a1 = x_src[f1 * DD + lane];
            float a2 = x_src[f2 * DD + lane];
            float a3 = x_src[f3 * DD + lane];
            acc += w0 * a0 + w1 * a1 + w2 * a2 + w3 * a3;
        }
        for (; j < cnt; j++) {
            int f0 = __shfl(nid, j, 64);
            acc += inv_src[f0] * x_src[f0 * DD + lane];
        }
    }
    int o = node * DD + lane;
    res[o] = x_dst[o] + COEF * inv_dst[node] * acc;
}

// ---------------- score ----------------

__global__ void score_kernel(const int* __restrict__ lm, const int* __restrict__ lu,
                             const float* __restrict__ ru, const float* __restrict__ rm,
                             float* __restrict__ scores) {
    int tid = blockIdx.x * blockDim.x + threadIdx.x;
    int l = tid >> 6;
    int d = threadIdx.x & 63;
    if (l < NL) {
        int u = lu[l];
        int m = lm[l];
        float v = ru[u * DD + d] * rm[m * DD + d];
        #pragma unroll
        for (int off = 32; off >= 1; off >>= 1)
            v += __shfl_down(v, off, 64);
        if (d == 0) scores[l] = v;
    }
}

// ---------------- fallback: round-3 scatter ----------------

__global__ void scatter_kernel_f(const int* __restrict__ ef, const int* __restrict__ et,
                                 int* __restrict__ cur_u, int* __restrict__ cur_m,
                                 int* __restrict__ pay_u, int* __restrict__ pay_m) {
    int tid = blockIdx.x * blockDim.x + threadIdx.x;
    int base = tid * 8;
    if (base >= NE) return;
    const int4* ef4 = (const int4*)(ef + base);
    const int4* et4 = (const int4*)(et + base);
    int4 fa = ef4[0], fb = ef4[1];
    int4 ta = et4[0], tb = et4[1];
    int f[8] = {fa.x, fa.y, fa.z, fa.w, fb.x, fb.y, fb.z, fb.w};
    int t[8] = {ta.x, ta.y, ta.z, ta.w, tb.x, tb.y, tb.z, tb.w};
    int su[8], sm[8];
    #pragma unroll
    for (int k = 0; k < 8; k++) su[k] = atomicAdd(&cur_u[t[k]], 1);
    #pragma unroll
    for (int k = 0; k < 8; k++) sm[k] = atomicAdd(&cur_m[f[k]], 1);
    #pragma unroll
    for (int k = 0; k < 8; k++) pay_u[su[k]] = f[k];
    #pragma unroll
    for (int k = 0; k < 8; k++) pay_m[sm[k]] = t[k];
}

// ---------------- fallback: atomic agg path ----------------

__global__ void degree_kernel_f(const int* __restrict__ ef, const int* __restrict__ et,
                                float* __restrict__ deg_m, float* __restrict__ deg_u) {
    int i = blockIdx.x * blockDim.x + threadIdx.x;
    if (i < NE) {
        atomicAdd(&deg_m[ef[i]], 1.0f);
        atomicAdd(&deg_u[et[i]], 1.0f);
    }
}

__global__ void inv_kernel_f(float* __restrict__ deg, int n) {
    int i = blockIdx.x * blockDim.x + threadIdx.x;
    if (i < n) {
        float d = deg[i];
        deg[i] = (d > 0.0f) ? (1.0f / sqrtf(d)) : 0.0f;
    }
}

__global__ void agg_kernel_f(const int* __restrict__ ef, const int* __restrict__ et,
                             const float* __restrict__ inv_m, const float* __restrict__ inv_u,
                             const float* __restrict__ x_u, const float* __restrict__ x_m,
                             float* __restrict__ res_u, float* __restrict__ res_m) {
    int tid = blockIdx.x * blockDim.x + threadIdx.x;
    int e = tid >> 6;
    int d = tid & 63;
    if (e < NE) {
        int f = ef[e];
        int t = et[e];
        float norm = inv_m[f] * inv_u[t] * COEF;
        atomicAdd(&res_u[t * DD + d], norm * x_m[f * DD + d]);
        atomicAdd(&res_m[f * DD + d], norm * x_u[t * DD + d]);
    }
}

__global__ void add_base_kernel_f(const float* __restrict__ xu, const float* __restrict__ xm,
                                  float* __restrict__ ru, float* __restrict__ rm) {
    int i = blockIdx.x * blockDim.x + threadIdx.x;
    const int nu = NU * DD;
    const int nm = NM * DD;
    if (i < nu) {
        ru[i] += xu[i];
    } else if (i < nu + nm) {
        int j = i - nu;
        rm[j] += xm[j];
    }
}

// ---------------- launch ----------------

extern "C" void kernel_launch(void* const* d_in, const int* in_sizes, int n_in,
                              void* d_out, int out_size, void* d_ws, size_t ws_size,
                              hipStream_t stream) {
    const float* emb_user  = (const float*)d_in[0];
    const float* emb_movie = (const float*)d_in[1];
    const int* edge_from   = (const int*)d_in[4];
    const int* edge_to     = (const int*)d_in[5];
    const int* label_movie = (const int*)d_in[6];
    const int* label_user  = (const int*)d_in[7];

    float* out    = (float*)d_out;
    float* scores = out;                              // [NL]
    float* res_u  = out + NL;                         // [NU*DD]
    float* res_m  = out + NL + (size_t)NU * DD;       // [NM*DD]

    // ws layout
    int*   deg_u  = (int*)d_ws;                       // NU
    int*   deg_m  = deg_u + NU;                       // NM
    int*   gbh_u  = deg_m + NM;                       // NB   (zeroed with deg)
    int*   gbh_m  = gbh_u + NB;                       // NB
    int*   rp_u   = gbh_m + NB;                       // NU+1
    int*   rp_m   = rp_u + NU + 1;                    // NM+1
    int*   cur_u  = rp_m + NM + 1;                    // NU
    int*   cur_m  = cur_u + NU;                       // NM
    float* inv_u  = (float*)(cur_m + NM);             // NU
    float* inv_m  = inv_u + NU;                       // NM
    int*   bo_u   = (int*)(inv_m + NM);               // NB+1
    int*   bcur_u = bo_u + NB + 1;                    // NB
    int*   bo_m   = bcur_u + NB;                      // NB+1
    int*   bcur_m = bo_m + NB + 1;                    // NB
    int*   part_u = bcur_m + NB;                      // NCH_U+1
    int*   part_m = part_u + NCH_U + 1;               // NCH_M+1
    int*   pay_u  = part_m + NCH_M + 1;               // NE
    int*   pay_m  = pay_u + NE;                       // NE
    size_t off    = (size_t)((pay_m + NE) - (int*)d_ws);
    off = (off + 3) & ~(size_t)3;                     // 16B-align stage
    int2*  stage  = (int2*)((int*)d_ws + off);        // NE int2

    size_t needed_new = (off + 2 * (size_t)NE) * sizeof(int);
    size_t needed_csr = ((size_t)(NU + NM) * 4 + 2 + 2 * (size_t)NE + 2 * NB + 2 * (NB + 1)
                         + NCH_U + NCH_M + 2) * sizeof(int);

    if (ws_size >= needed_csr) {
        hipMemsetAsync(deg_u, 0, ((size_t)(NU + NM) + 2 * NB) * sizeof(int), stream);

        hist_kernel<<<(NE + 1023) / 1024, 256, 0, stream>>>(
            edge_from, edge_to, deg_m, deg_u, gbh_u, gbh_m);
        inv_from_deg_kernel<<<(NU + NM + 255) / 256, 256, 0, stream>>>(deg_u, inv_u, NU + NM);

        // deg -> rp/cur (3-phase)
        chunk_sum_kernel<<<NCH_U, 256, 0, stream>>>(deg_u, part_u, NU);
        chunk_sum_kernel<<<NCH_M, 256, 0, stream>>>(deg_m, part_m, NM);
        scan_small_kernel<<<1, 256, 0, stream>>>(part_u, part_u, nullptr, NCH_U);
        scan_small_kernel<<<1, 256, 0, stream>>>(part_m, part_m, nullptr, NCH_M);
        chunk_scan_kernel<<<NCH_U, 256, 0, stream>>>(deg_u, part_u, rp_u, cur_u, NU, NCH_U);
        chunk_scan_kernel<<<NCH_M, 256, 0, stream>>>(deg_m, part_m, rp_m, cur_m, NM, NCH_M);

        if (ws_size >= needed_new) {
            // bucket offsets/cursors
            scan_small_kernel<<<1, 256, 0, stream>>>(gbh_u, bo_u, bcur_u, NB);
            scan_small_kernel<<<1, 256, 0, stream>>>(gbh_m, bo_m, bcur_m, NB);

            // u-side: key = user t, val = movie f
            partition_kernel<<<(NE + 4095) / 4096, 256, 0, stream>>>(
                edge_to, edge_from, bcur_u, stage, SHIFT_U);
            fine_kernel<<<(NE + 2047) / 2048, 256, 0, stream>>>(stage, cur_u, pay_u);
            // m-side: key = movie f, val = user t
            partition_kernel<<<(NE + 4095) / 4096, 256, 0, stream>>>(
                edge_from, edge_to, bcur_m, stage, SHIFT_M);
            fine_kernel<<<(NE + 2047) / 2048, 256, 0, stream>>>(stage, cur_m, pay_m);
        } else {
            scatter_kernel_f<<<(NE / 8 + 255) / 256, 256, 0, stream>>>(
                edge_from, edge_to, cur_u, cur_m, pay_u, pay_m);
        }

        gather_kernel<<<((size_t)NU * 64 + 255) / 256, 256, 0, stream>>>(
            rp_u, pay_u, inv_u, inv_m, emb_movie, emb_user, res_u, NU);
        gather_kernel<<<((size_t)NM * 64 + 255) / 256, 256, 0, stream>>>(
            rp_m, pay_m, inv_m, inv_u, emb_user, emb_movie, res_m, NM);
    } else {
        // ---- fallback: atomic path ----
        float* fdeg_u = (float*)d_ws;
        float* fdeg_m = fdeg_u + NU;
        hipMemsetAsync(res_u, 0, (size_t)(NU + NM) * DD * sizeof(float), stream);
        hipMemsetAsync(fdeg_u, 0, (size_t)(NU + NM) * sizeof(float), stream);
        degree_kernel_f<<<(NE + 255) / 256, 256, 0, stream>>>(edge_from, edge_to, fdeg_m, fdeg_u);
        inv_kernel_f<<<(NU + NM + 255) / 256, 256, 0, stream>>>(fdeg_u, NU + NM);
        agg_kernel_f<<<((size_t)NE * 64 + 255) / 256, 256, 0, stream>>>(
            edge_from, edge_to, fdeg_m, fdeg_u, emb_user, emb_movie, res_u, res_m);
        add_base_kernel_f<<<((NU + NM) * DD + 255) / 256, 256, 0, stream>>>(
            emb_user, emb_movie, res_u, res_m);
    }

    score_kernel<<<((size_t)NL * 64 + 255) / 256, 256, 0, stream>>>(
        label_movie, label_user, res_u, res_m, scores);
}

// Round 5
// 749.538 us; speedup vs baseline: 3.6138x; 1.9511x over previous
//
#include <hip/hip_runtime.h>

#define NU 160000
#define NM 60000
#define DD 64
#define NE 5000000
#define NL 200000

// res = x + (1/2 + 1/3 + 1/4) * agg = x + (13/12)*agg  (all layers propagate layer-0)
#define COEF (13.0f / 12.0f)

#define SHIFT_U 9                               // 512 users/bucket
#define SHIFT_M 7                               // 128 movies/bucket
#define NBU ((NU + (1 << SHIFT_U) - 1) >> SHIFT_U)   // 313
#define NBM ((NM + (1 << SHIFT_M) - 1) >> SHIFT_M)   // 469

// ---------------- pass A: bucket counts only ----------------

#define CEC 16   // edges/thread

__global__ void bucket_count_kernel(const int* __restrict__ ef, const int* __restrict__ et,
                                    int* __restrict__ gbh_u, int* __restrict__ gbh_m) {
    __shared__ int bhu[NBU], bhm[NBM];
    int tid = threadIdx.x;
    for (int i = tid; i < NBU; i += 256) bhu[i] = 0;
    for (int i = tid; i < NBM; i += 256) bhm[i] = 0;
    __syncthreads();
    int base = (blockIdx.x * 256 + tid) * CEC;
    if (base < NE) {   // NE % 16 == 0 -> all-or-none
        const int4* f4 = (const int4*)(ef + base);
        const int4* t4 = (const int4*)(et + base);
        #pragma unroll
        for (int q = 0; q < CEC / 4; q++) {
            int4 ff = f4[q]; int4 tt = t4[q];
            atomicAdd(&bhm[ff.x >> SHIFT_M], 1); atomicAdd(&bhu[tt.x >> SHIFT_U], 1);
            atomicAdd(&bhm[ff.y >> SHIFT_M], 1); atomicAdd(&bhu[tt.y >> SHIFT_U], 1);
            atomicAdd(&bhm[ff.z >> SHIFT_M], 1); atomicAdd(&bhu[tt.z >> SHIFT_U], 1);
            atomicAdd(&bhm[ff.w >> SHIFT_M], 1); atomicAdd(&bhu[tt.w >> SHIFT_U], 1);
        }
    }
    __syncthreads();
    for (int i = tid; i < NBU; i += 256) if (bhu[i]) atomicAdd(&gbh_u[i], bhu[i]);
    for (int i = tid; i < NBM; i += 256) if (bhm[i]) atomicAdd(&gbh_m[i], bhm[i]);
}

// ---------------- small exclusive scan (n <= 1024); out[n]=total; cursor copy ----------------

__global__ void scan_small_kernel(const int* __restrict__ in, int* __restrict__ out,
                                  int* __restrict__ cur, int n) {
    __shared__ int buf[256];
    int tid = threadIdx.x;
    int idx = tid * 4;
    int v0 = (idx + 0 < n) ? in[idx + 0] : 0;
    int v1 = (idx + 1 < n) ? in[idx + 1] : 0;
    int v2 = (idx + 2 < n) ? in[idx + 2] : 0;
    int v3 = (idx + 3 < n) ? in[idx + 3] : 0;
    int s = v0 + v1 + v2 + v3;
    buf[tid] = s;
    __syncthreads();
    for (int off = 1; off < 256; off <<= 1) {
        int t = (tid >= off) ? buf[tid - off] : 0;
        __syncthreads();
        buf[tid] += t;
        __syncthreads();
    }
    int p = buf[tid] - s;
    if (idx + 0 < n) { out[idx + 0] = p; if (cur) cur[idx + 0] = p; p += v0; }
    if (idx + 1 < n) { out[idx + 1] = p; if (cur) cur[idx + 1] = p; p += v1; }
    if (idx + 2 < n) { out[idx + 2] = p; if (cur) cur[idx + 2] = p; p += v2; }
    if (idx + 3 < n) { out[idx + 3] = p; if (cur) cur[idx + 3] = p; p += v3; }
    if (tid == 255) out[n] = buf[255];
}

// ---------------- coarse partition into bucket-grouped staging ----------------

#define PEC 16   // edges/thread; 4096/block

__global__ void partition_kernel(const int* __restrict__ key, const int* __restrict__ val,
                                 int* __restrict__ bcur, int2* __restrict__ stage,
                                 int shift, int nb) {
    __shared__ int lh[512];
    __shared__ int lbase[512];
    int tid = threadIdx.x;
    for (int i = tid; i < nb; i += 256) lh[i] = 0;
    __syncthreads();
    int base = (blockIdx.x * 256 + tid) * PEC;
    int k_[PEC], v_[PEC], br_[PEC];
    bool act = base < NE;   // NE % 16 == 0 -> all-or-none
    if (act) {
        const int4* k4 = (const int4*)(key + base);
        const int4* v4 = (const int4*)(val + base);
        #pragma unroll
        for (int q = 0; q < PEC / 4; q++) {
            int4 kk = k4[q]; int4 vv = v4[q];
            k_[q * 4 + 0] = kk.x; k_[q * 4 + 1] = kk.y; k_[q * 4 + 2] = kk.z; k_[q * 4 + 3] = kk.w;
            v_[q * 4 + 0] = vv.x; v_[q * 4 + 1] = vv.y; v_[q * 4 + 2] = vv.z; v_[q * 4 + 3] = vv.w;
        }
        #pragma unroll
        for (int q = 0; q < PEC; q++) {
            int b = k_[q] >> shift;
            int r = atomicAdd(&lh[b], 1);       // rank within (block,bucket) < 4096
            br_[q] = (b << 13) | r;
        }
    }
    __syncthreads();
    for (int i = tid; i < nb; i += 256) lbase[i] = lh[i] ? atomicAdd(&bcur[i], lh[i]) : 0;
    __syncthreads();
    if (act) {
        #pragma unroll
        for (int q = 0; q < PEC; q++) {
            int b = br_[q] >> 13;
            int r = br_[q] & 8191;
            stage[lbase[b] + r] = make_int2(k_[q], v_[q]);
        }
    }
}

// ---------------- per-bucket build: deg+inv+rp+pay, all in LDS, zero global atomics ----------------

// one block per bucket; bucket b owns nodes [b<<shift, ...) and stage segment [bo[b], bo[b+1])
__global__ void build_kernel(const int2* __restrict__ stage, const int* __restrict__ bo,
                             float* __restrict__ inv, int* __restrict__ rp,
                             int* __restrict__ pay, int shift, int n) {
    __shared__ int cnt[512];
    __shared__ int tmp[512];
    int b = blockIdx.x;
    int tid = threadIdx.x;
    int bs = 1 << shift;
    int base = b << shift;
    int nn = min(bs, n - base);          // nodes actually in this bucket
    int s0 = bo[b];
    int s1 = bo[b + 1];

    for (int i = tid; i < bs; i += 256) cnt[i] = 0;
    __syncthreads();
    // pass 1: histogram
    for (int e = s0 + tid; e < s1; e += 256)
        atomicAdd(&cnt[stage[e].x - base], 1);
    __syncthreads();
    // save originals (each thread owns i = tid, tid+256)
    int o0 = (tid < bs) ? cnt[tid] : 0;
    int o1 = (tid + 256 < bs) ? cnt[tid + 256] : 0;
    // inclusive scan (Hillis-Steele, ping-pong)
    for (int off = 1; off < bs; off <<= 1) {
        for (int i = tid; i < bs; i += 256) tmp[i] = (i >= off) ? cnt[i - off] : 0;
        __syncthreads();
        for (int i = tid; i < bs; i += 256) cnt[i] += tmp[i];
        __syncthreads();
    }
    // exclusive + write rp/inv, set LDS cursors
    if (tid < bs) {
        int excl = cnt[tid] - o0;
        tmp[tid] = s0 + excl;
        if (tid < nn) {
            rp[base + tid] = s0 + excl;
            inv[base + tid] = (o0 > 0) ? rsqrtf((float)o0) : 0.0f;
        }
    }
    if (tid + 256 < bs) {
        int i = tid + 256;
        int excl = cnt[i] - o1;
        tmp[i] = s0 + excl;
        if (i < nn) {
            rp[base + i] = s0 + excl;
            inv[base + i] = (o1 > 0) ? rsqrtf((float)o1) : 0.0f;
        }
    }
    if (b == 0 && tid == 0) rp[n] = NE;
    __syncthreads();
    // pass 2: place payloads via LDS cursors
    for (int e = s0 + tid; e < s1; e += 256) {
        int2 p = stage[e];
        int pos = atomicAdd(&tmp[p.x - base], 1);
        pay[pos] = p.y;
    }
}

// ---------------- gather ----------------

__global__ void gather_kernel(const int* __restrict__ rp, const int* __restrict__ pay,
                              const float* __restrict__ inv_dst, const float* __restrict__ inv_src,
                              const float* __restrict__ x_src, const float* __restrict__ x_dst,
                              float* __restrict__ res, int n) {
    int tid = blockIdx.x * blockDim.x + threadIdx.x;
    int node = tid >> 6;
    int lane = threadIdx.x & 63;
    if (node >= n) return;
    int start = rp[node];
    int end   = rp[node + 1];
    float acc = 0.0f;
    for (int i = start; i < end; i += 64) {
        int cnt = min(end - i, 64);
        int nid = (lane < cnt) ? pay[i + lane] : 0;
        int j = 0;
        for (; j + 4 <= cnt; j += 4) {
            int f0 = __shfl(nid, j + 0, 64);
            int f1 = __shfl(nid, j + 1, 64);
            int f2 = __shfl(nid, j + 2, 64);
            int f3 = __shfl(nid, j + 3, 64);
            float w0 = inv_src[f0], w1 = inv_src[f1], w2 = inv_src[f2], w3 = inv_src[f3];
            float a0 = x_src[f0 * DD + lane];
            float a1 = x_src[f1 * DD + lane];
            float a2 = x_src[f2 * DD + lane];
            float a3 = x_src[f3 * DD + lane];
            acc += w0 * a0 + w1 * a1 + w2 * a2 + w3 * a3;
        }
        for (; j < cnt; j++) {
            int f0 = __shfl(nid, j, 64);
            acc += inv_src[f0] * x_src[f0 * DD + lane];
        }
    }
    int o = node * DD + lane;
    res[o] = x_dst[o] + COEF * inv_dst[node] * acc;
}

// ---------------- score ----------------

__global__ void score_kernel(const int* __restrict__ lm, const int* __restrict__ lu,
                             const float* __restrict__ ru, const float* __restrict__ rm,
                             float* __restrict__ scores) {
    int tid = blockIdx.x * blockDim.x + threadIdx.x;
    int l = tid >> 6;
    int d = threadIdx.x & 63;
    if (l < NL) {
        int u = lu[l];
        int m = lm[l];
        float v = ru[u * DD + d] * rm[m * DD + d];
        #pragma unroll
        for (int off = 32; off >= 1; off >>= 1)
            v += __shfl_down(v, off, 64);
        if (d == 0) scores[l] = v;
    }
}

// ---------------- fallback: atomic agg path ----------------

__global__ void degree_kernel_f(const int* __restrict__ ef, const int* __restrict__ et,
                                float* __restrict__ deg_m, float* __restrict__ deg_u) {
    int i = blockIdx.x * blockDim.x + threadIdx.x;
    if (i < NE) {
        atomicAdd(&deg_m[ef[i]], 1.0f);
        atomicAdd(&deg_u[et[i]], 1.0f);
    }
}

__global__ void inv_kernel_f(float* __restrict__ deg, int n) {
    int i = blockIdx.x * blockDim.x + threadIdx.x;
    if (i < n) {
        float d = deg[i];
        deg[i] = (d > 0.0f) ? (1.0f / sqrtf(d)) : 0.0f;
    }
}

__global__ void agg_kernel_f(const int* __restrict__ ef, const int* __restrict__ et,
                             const float* __restrict__ inv_m, const float* __restrict__ inv_u,
                             const float* __restrict__ x_u, const float* __restrict__ x_m,
                             float* __restrict__ res_u, float* __restrict__ res_m) {
    int tid = blockIdx.x * blockDim.x + threadIdx.x;
    int e = tid >> 6;
    int d = tid & 63;
    if (e < NE) {
        int f = ef[e];
        int t = et[e];
        float norm = inv_m[f] * inv_u[t] * COEF;
        atomicAdd(&res_u[t * DD + d], norm * x_m[f * DD + d]);
        atomicAdd(&res_m[f * DD + d], norm * x_u[t * DD + d]);
    }
}

__global__ void add_base_kernel_f(const float* __restrict__ xu, const float* __restrict__ xm,
                                  float* __restrict__ ru, float* __restrict__ rm) {
    int i = blockIdx.x * blockDim.x + threadIdx.x;
    const int nu = NU * DD;
    const int nm = NM * DD;
    if (i < nu) {
        ru[i] += xu[i];
    } else if (i < nu + nm) {
        int j = i - nu;
        rm[j] += xm[j];
    }
}

// ---------------- launch ----------------

extern "C" void kernel_launch(void* const* d_in, const int* in_sizes, int n_in,
                              void* d_out, int out_size, void* d_ws, size_t ws_size,
                              hipStream_t stream) {
    const float* emb_user  = (const float*)d_in[0];
    const float* emb_movie = (const float*)d_in[1];
    const int* edge_from   = (const int*)d_in[4];
    const int* edge_to     = (const int*)d_in[5];
    const int* label_movie = (const int*)d_in[6];
    const int* label_user  = (const int*)d_in[7];

    float* out    = (float*)d_out;
    float* scores = out;                              // [NL]
    float* res_u  = out + NL;                         // [NU*DD]
    float* res_m  = out + NL + (size_t)NU * DD;       // [NM*DD]

    // ws layout
    int*   gbh_u  = (int*)d_ws;                       // NBU  (zeroed)
    int*   gbh_m  = gbh_u + NBU;                      // NBM  (zeroed)
    int*   bo_u   = gbh_m + NBM;                      // NBU+1
    int*   bcur_u = bo_u + NBU + 1;                   // NBU
    int*   bo_m   = bcur_u + NBU;                     // NBM+1
    int*   bcur_m = bo_m + NBM + 1;                   // NBM
    float* inv_u  = (float*)(bcur_m + NBM);           // NU
    float* inv_m  = inv_u + NU;                       // NM
    int*   rp_u   = (int*)(inv_m + NM);               // NU+1
    int*   rp_m   = rp_u + NU + 1;                    // NM+1
    int*   pay_u  = rp_m + NM + 1;                    // NE
    int*   pay_m  = pay_u + NE;                       // NE
    size_t off    = (size_t)((pay_m + NE) - (int*)d_ws);
    off = (off + 3) & ~(size_t)3;                     // 16B-align stage
    int2*  stage  = (int2*)((int*)d_ws + off);        // NE int2

    size_t needed = (off + 2 * (size_t)NE) * sizeof(int);

    if (ws_size >= needed) {
        hipMemsetAsync(gbh_u, 0, (size_t)(NBU + NBM) * sizeof(int), stream);

        bucket_count_kernel<<<(NE / CEC + 255) / 256, 256, 0, stream>>>(
            edge_from, edge_to, gbh_u, gbh_m);
        scan_small_kernel<<<1, 256, 0, stream>>>(gbh_u, bo_u, bcur_u, NBU);
        scan_small_kernel<<<1, 256, 0, stream>>>(gbh_m, bo_m, bcur_m, NBM);

        // u-side: key = user (edge_to), val = movie (edge_from)
        partition_kernel<<<(NE / PEC + 255) / 256, 256, 0, stream>>>(
            edge_to, edge_from, bcur_u, stage, SHIFT_U, NBU);
        build_kernel<<<NBU, 256, 0, stream>>>(stage, bo_u, inv_u, rp_u, pay_u, SHIFT_U, NU);

        // m-side: key = movie (edge_from), val = user (edge_to)
        partition_kernel<<<(NE / PEC + 255) / 256, 256, 0, stream>>>(
            edge_from, edge_to, bcur_m, stage, SHIFT_M, NBM);
        build_kernel<<<NBM, 256, 0, stream>>>(stage, bo_m, inv_m, rp_m, pay_m, SHIFT_M, NM);

        gather_kernel<<<((size_t)NU * 64 + 255) / 256, 256, 0, stream>>>(
            rp_u, pay_u, inv_u, inv_m, emb_movie, emb_user, res_u, NU);
        gather_kernel<<<((size_t)NM * 64 + 255) / 256, 256, 0, stream>>>(
            rp_m, pay_m, inv_m, inv_u, emb_user, emb_movie, res_m, NM);
    } else {
        // ---- fallback: atomic path ----
        float* fdeg_u = (float*)d_ws;
        float* fdeg_m = fdeg_u + NU;
        hipMemsetAsync(res_u, 0, (size_t)(NU + NM) * DD * sizeof(float), stream);
        hipMemsetAsync(fdeg_u, 0, (size_t)(NU + NM) * sizeof(float), stream);
        degree_kernel_f<<<(NE + 255) / 256, 256, 0, stream>>>(edge_from, edge_to, fdeg_m, fdeg_u);
        inv_kernel_f<<<(NU + NM + 255) / 256, 256, 0, stream>>>(fdeg_u, NU + NM);
        agg_kernel_f<<<((size_t)NE * 64 + 255) / 256, 256, 0, stream>>>(
            edge_from, edge_to, fdeg_m, fdeg_u, emb_user, emb_movie, res_u, res_m);
        add_base_kernel_f<<<((NU + NM) * DD + 255) / 256, 256, 0, stream>>>(
            emb_user, emb_movie, res_u, res_m);
    }

    score_kernel<<<((size_t)NL * 64 + 255) / 256, 256, 0, stream>>>(
        label_movie, label_user, res_u, res_m, scores);
}

// Round 6
// 717.242 us; speedup vs baseline: 3.7765x; 1.0450x over previous
//
#include <hip/hip_runtime.h>
#include <hip/hip_bf16.h>

#define NU 160000
#define NM 60000
#define DD 64
#define NE 5000000
#define NL 200000

// res = x + (1/2 + 1/3 + 1/4) * agg = x + (13/12)*agg  (all layers propagate layer-0)
#define COEF (13.0f / 12.0f)

#define SHIFT_U 9                               // 512 users/bucket
#define SHIFT_M 7                               // 128 movies/bucket
#define NBU ((NU + (1 << SHIFT_U) - 1) >> SHIFT_U)   // 313
#define NBM ((NM + (1 << SHIFT_M) - 1) >> SHIFT_M)   // 469
#define VB_U 16   // movie id fits 16 bits (60000 < 65536)
#define VB_M 18   // user id fits 18 bits (160000 < 262144)

// ---------------- pass A: bucket counts only ----------------

#define CEC 16   // edges/thread

__global__ void bucket_count_kernel(const int* __restrict__ ef, const int* __restrict__ et,
                                    int* __restrict__ gbh_u, int* __restrict__ gbh_m) {
    __shared__ int bhu[NBU], bhm[NBM];
    int tid = threadIdx.x;
    for (int i = tid; i < NBU; i += 256) bhu[i] = 0;
    for (int i = tid; i < NBM; i += 256) bhm[i] = 0;
    __syncthreads();
    int base = (blockIdx.x * 256 + tid) * CEC;
    if (base < NE) {   // NE % 16 == 0 -> all-or-none
        const int4* f4 = (const int4*)(ef + base);
        const int4* t4 = (const int4*)(et + base);
        #pragma unroll
        for (int q = 0; q < CEC / 4; q++) {
            int4 ff = f4[q]; int4 tt = t4[q];
            atomicAdd(&bhm[ff.x >> SHIFT_M], 1); atomicAdd(&bhu[tt.x >> SHIFT_U], 1);
            atomicAdd(&bhm[ff.y >> SHIFT_M], 1); atomicAdd(&bhu[tt.y >> SHIFT_U], 1);
            atomicAdd(&bhm[ff.z >> SHIFT_M], 1); atomicAdd(&bhu[tt.z >> SHIFT_U], 1);
            atomicAdd(&bhm[ff.w >> SHIFT_M], 1); atomicAdd(&bhu[tt.w >> SHIFT_U], 1);
        }
    }
    __syncthreads();
    for (int i = tid; i < NBU; i += 256) if (bhu[i]) atomicAdd(&gbh_u[i], bhu[i]);
    for (int i = tid; i < NBM; i += 256) if (bhm[i]) atomicAdd(&gbh_m[i], bhm[i]);
}

// ---------------- small exclusive scan (n <= 1024); out[n]=total; cursor copy ----------------

__global__ void scan_small_kernel(const int* __restrict__ in, int* __restrict__ out,
                                  int* __restrict__ cur, int n) {
    __shared__ int buf[256];
    int tid = threadIdx.x;
    int idx = tid * 4;
    int v0 = (idx + 0 < n) ? in[idx + 0] : 0;
    int v1 = (idx + 1 < n) ? in[idx + 1] : 0;
    int v2 = (idx + 2 < n) ? in[idx + 2] : 0;
    int v3 = (idx + 3 < n) ? in[idx + 3] : 0;
    int s = v0 + v1 + v2 + v3;
    buf[tid] = s;
    __syncthreads();
    for (int off = 1; off < 256; off <<= 1) {
        int t = (tid >= off) ? buf[tid - off] : 0;
        __syncthreads();
        buf[tid] += t;
        __syncthreads();
    }
    int p = buf[tid] - s;
    if (idx + 0 < n) { out[idx + 0] = p; if (cur) cur[idx + 0] = p; p += v0; }
    if (idx + 1 < n) { out[idx + 1] = p; if (cur) cur[idx + 1] = p; p += v1; }
    if (idx + 2 < n) { out[idx + 2] = p; if (cur) cur[idx + 2] = p; p += v2; }
    if (idx + 3 < n) { out[idx + 3] = p; if (cur) cur[idx + 3] = p; p += v3; }
    if (tid == 255) out[n] = buf[255];
}

// ---------------- coarse partition into bucket-grouped staging (packed int32) ----------------

#define PEC 16   // edges/thread; 4096/block

__global__ void partition_kernel(const int* __restrict__ key, const int* __restrict__ val,
                                 int* __restrict__ bcur, int* __restrict__ stage,
                                 int shift, int nb, int valbits) {
    __shared__ int lh[512];
    __shared__ int lbase[512];
    int tid = threadIdx.x;
    int lmask = (1 << shift) - 1;
    for (int i = tid; i < nb; i += 256) lh[i] = 0;
    __syncthreads();
    int base = (blockIdx.x * 256 + tid) * PEC;
    int k_[PEC], v_[PEC], br_[PEC];
    bool act = base < NE;   // NE % 16 == 0 -> all-or-none
    if (act) {
        const int4* k4 = (const int4*)(key + base);
        const int4* v4 = (const int4*)(val + base);
        #pragma unroll
        for (int q = 0; q < PEC / 4; q++) {
            int4 kk = k4[q]; int4 vv = v4[q];
            k_[q * 4 + 0] = kk.x; k_[q * 4 + 1] = kk.y; k_[q * 4 + 2] = kk.z; k_[q * 4 + 3] = kk.w;
            v_[q * 4 + 0] = vv.x; v_[q * 4 + 1] = vv.y; v_[q * 4 + 2] = vv.z; v_[q * 4 + 3] = vv.w;
        }
        #pragma unroll
        for (int q = 0; q < PEC; q++) {
            int b = k_[q] >> shift;
            int r = atomicAdd(&lh[b], 1);       // rank within (block,bucket) < 4096
            br_[q] = (b << 13) | r;
        }
    }
    __syncthreads();
    for (int i = tid; i < nb; i += 256) lbase[i] = lh[i] ? atomicAdd(&bcur[i], lh[i]) : 0;
    __syncthreads();
    if (act) {
        #pragma unroll
        for (int q = 0; q < PEC; q++) {
            int b = br_[q] >> 13;
            int r = br_[q] & 8191;
            stage[lbase[b] + r] = ((k_[q] & lmask) << valbits) | v_[q];
        }
    }
}

// ---------------- per-bucket build: deg+inv+rp+pay, all in LDS ----------------

__global__ void build_kernel(const int* __restrict__ stage, const int* __restrict__ bo,
                             float* __restrict__ inv, int* __restrict__ rp,
                             int* __restrict__ pay, int shift, int n, int valbits) {
    __shared__ int cnt[512];
    __shared__ int tmp[512];
    int b = blockIdx.x;
    int tid = threadIdx.x;
    int bs = 1 << shift;
    int base = b << shift;
    int nn = min(bs, n - base);
    int vmask = (1 << valbits) - 1;
    int s0 = bo[b];
    int s1 = bo[b + 1];

    for (int i = tid; i < bs; i += 256) cnt[i] = 0;
    __syncthreads();
    // pass 1: histogram over bucket-local keys
    for (int e = s0 + tid; e < s1; e += 256)
        atomicAdd(&cnt[stage[e] >> valbits], 1);
    __syncthreads();
    int o0 = (tid < bs) ? cnt[tid] : 0;
    int o1 = (tid + 256 < bs) ? cnt[tid + 256] : 0;
    // inclusive scan (Hillis-Steele)
    for (int off = 1; off < bs; off <<= 1) {
        for (int i = tid; i < bs; i += 256) tmp[i] = (i >= off) ? cnt[i - off] : 0;
        __syncthreads();
        for (int i = tid; i < bs; i += 256) cnt[i] += tmp[i];
        __syncthreads();
    }
    if (tid < bs) {
        int excl = cnt[tid] - o0;
        tmp[tid] = s0 + excl;
        if (tid < nn) {
            rp[base + tid] = s0 + excl;
            inv[base + tid] = (o0 > 0) ? rsqrtf((float)o0) : 0.0f;
        }
    }
    if (tid + 256 < bs) {
        int i = tid + 256;
        int excl = cnt[i] - o1;
        tmp[i] = s0 + excl;
        if (i < nn) {
            rp[base + i] = s0 + excl;
            inv[base + i] = (o1 > 0) ? rsqrtf((float)o1) : 0.0f;
        }
    }
    if (b == 0 && tid == 0) rp[n] = NE;
    __syncthreads();
    // pass 2: place payloads via LDS cursors
    for (int e = s0 + tid; e < s1; e += 256) {
        int p = stage[e];
        int pos = atomicAdd(&tmp[p >> valbits], 1);
        pay[pos] = p & vmask;
    }
}

// ---------------- prescale: y = bf16(inv_src * x_src) ----------------

__global__ void prescale_kernel(const float* __restrict__ x, const float* __restrict__ inv,
                                __hip_bfloat16* __restrict__ y, int total) {
    int i = blockIdx.x * blockDim.x + threadIdx.x;
    if (i < total) {
        int node = i >> 6;
        y[i] = __float2bfloat16(inv[node] * x[i]);
    }
}

// ---------------- gather (bf16 prescaled source rows) ----------------

__global__ void gather_kernel(const int* __restrict__ rp, const int* __restrict__ pay,
                              const float* __restrict__ inv_dst,
                              const __hip_bfloat16* __restrict__ y_src,
                              const float* __restrict__ x_dst,
                              float* __restrict__ res, int n) {
    int tid = blockIdx.x * blockDim.x + threadIdx.x;
    int node = tid >> 6;
    int lane = threadIdx.x & 63;
    if (node >= n) return;
    int start = rp[node];
    int end   = rp[node + 1];
    float acc = 0.0f;
    for (int i = start; i < end; i += 64) {
        int cnt = min(end - i, 64);
        int nid = (lane < cnt) ? pay[i + lane] : 0;
        int j = 0;
        for (; j + 4 <= cnt; j += 4) {
            int f0 = __shfl(nid, j + 0, 64);
            int f1 = __shfl(nid, j + 1, 64);
            int f2 = __shfl(nid, j + 2, 64);
            int f3 = __shfl(nid, j + 3, 64);
            float a0 = __bfloat162float(y_src[f0 * DD + lane]);
            float a1 = __bfloat162float(y_src[f1 * DD + lane]);
            float a2 = __bfloat162float(y_src[f2 * DD + lane]);
            float a3 = __bfloat162float(y_src[f3 * DD + lane]);
            acc += a0 + a1 + a2 + a3;
        }
        for (; j < cnt; j++) {
            int f0 = __shfl(nid, j, 64);
            acc += __bfloat162float(y_src[f0 * DD + lane]);
        }
    }
    int o = node * DD + lane;
    res[o] = x_dst[o] + COEF * inv_dst[node] * acc;
}

// ---------------- score ----------------

__global__ void score_kernel(const int* __restrict__ lm, const int* __restrict__ lu,
                             const float* __restrict__ ru, const float* __restrict__ rm,
                             float* __restrict__ scores) {
    int tid = blockIdx.x * blockDim.x + threadIdx.x;
    int l = tid >> 6;
    int d = threadIdx.x & 63;
    if (l < NL) {
        int u = lu[l];
        int m = lm[l];
        float v = ru[u * DD + d] * rm[m * DD + d];
        #pragma unroll
        for (int off = 32; off >= 1; off >>= 1)
            v += __shfl_down(v, off, 64);
        if (d == 0) scores[l] = v;
    }
}

// ---------------- fallback: atomic agg path ----------------

__global__ void degree_kernel_f(const int* __restrict__ ef, const int* __restrict__ et,
                                float* __restrict__ deg_m, float* __restrict__ deg_u) {
    int i = blockIdx.x * blockDim.x + threadIdx.x;
    if (i < NE) {
        atomicAdd(&deg_m[ef[i]], 1.0f);
        atomicAdd(&deg_u[et[i]], 1.0f);
    }
}

__global__ void inv_kernel_f(float* __restrict__ deg, int n) {
    int i = blockIdx.x * blockDim.x + threadIdx.x;
    if (i < n) {
        float d = deg[i];
        deg[i] = (d > 0.0f) ? (1.0f / sqrtf(d)) : 0.0f;
    }
}

__global__ void agg_kernel_f(const int* __restrict__ ef, const int* __restrict__ et,
                             const float* __restrict__ inv_m, const float* __restrict__ inv_u,
                             const float* __restrict__ x_u, const float* __restrict__ x_m,
                             float* __restrict__ res_u, float* __restrict__ res_m) {
    int tid = blockIdx.x * blockDim.x + threadIdx.x;
    int e = tid >> 6;
    int d = tid & 63;
    if (e < NE) {
        int f = ef[e];
        int t = et[e];
        float norm = inv_m[f] * inv_u[t] * COEF;
        atomicAdd(&res_u[t * DD + d], norm * x_m[f * DD + d]);
        atomicAdd(&res_m[f * DD + d], norm * x_u[t * DD + d]);
    }
}

__global__ void add_base_kernel_f(const float* __restrict__ xu, const float* __restrict__ xm,
                                  float* __restrict__ ru, float* __restrict__ rm) {
    int i = blockIdx.x * blockDim.x + threadIdx.x;
    const int nu = NU * DD;
    const int nm = NM * DD;
    if (i < nu) {
        ru[i] += xu[i];
    } else if (i < nu + nm) {
        int j = i - nu;
        rm[j] += xm[j];
    }
}

// ---------------- launch ----------------

extern "C" void kernel_launch(void* const* d_in, const int* in_sizes, int n_in,
                              void* d_out, int out_size, void* d_ws, size_t ws_size,
                              hipStream_t stream) {
    const float* emb_user  = (const float*)d_in[0];
    const float* emb_movie = (const float*)d_in[1];
    const int* edge_from   = (const int*)d_in[4];
    const int* edge_to     = (const int*)d_in[5];
    const int* label_movie = (const int*)d_in[6];
    const int* label_user  = (const int*)d_in[7];

    float* out    = (float*)d_out;
    float* scores = out;                              // [NL]
    float* res_u  = out + NL;                         // [NU*DD]
    float* res_m  = out + NL + (size_t)NU * DD;       // [NM*DD]

    // ws layout
    int*   gbh_u  = (int*)d_ws;                       // NBU  (zeroed)
    int*   gbh_m  = gbh_u + NBU;                      // NBM  (zeroed)
    int*   bo_u   = gbh_m + NBM;                      // NBU+1
    int*   bcur_u = bo_u + NBU + 1;                   // NBU
    int*   bo_m   = bcur_u + NBU;                     // NBM+1
    int*   bcur_m = bo_m + NBM + 1;                   // NBM
    float* inv_u  = (float*)(bcur_m + NBM);           // NU
    float* inv_m  = inv_u + NU;                       // NM
    int*   rp_u   = (int*)(inv_m + NM);               // NU+1
    int*   rp_m   = rp_u + NU + 1;                    // NM+1
    int*   pay_u  = rp_m + NM + 1;                    // NE
    int*   pay_m  = pay_u + NE;                       // NE
    // union region: stage (NE ints, dead after builds) then y_u/y_m (bf16)
    int*   ureg   = pay_m + NE;
    int*   stage  = ureg;                             // NE ints
    __hip_bfloat16* y_u = (__hip_bfloat16*)ureg;                      // NU*DD bf16
    __hip_bfloat16* y_m = (__hip_bfloat16*)(ureg + (size_t)NU * DD / 2); // NM*DD bf16

    size_t ysz    = (size_t)(NU + NM) * DD / 2;       // ints for y region
    size_t uni    = (size_t)NE > ysz ? (size_t)NE : ysz;
    size_t needed = ((size_t)(ureg - (int*)d_ws) + uni) * sizeof(int);

    if (ws_size >= needed) {
        hipMemsetAsync(gbh_u, 0, (size_t)(NBU + NBM) * sizeof(int), stream);

        bucket_count_kernel<<<(NE / CEC + 255) / 256, 256, 0, stream>>>(
            edge_from, edge_to, gbh_u, gbh_m);
        scan_small_kernel<<<1, 256, 0, stream>>>(gbh_u, bo_u, bcur_u, NBU);
        scan_small_kernel<<<1, 256, 0, stream>>>(gbh_m, bo_m, bcur_m, NBM);

        // u-side: key = user (edge_to), val = movie (edge_from)
        partition_kernel<<<(NE / PEC + 255) / 256, 256, 0, stream>>>(
            edge_to, edge_from, bcur_u, stage, SHIFT_U, NBU, VB_U);
        build_kernel<<<NBU, 256, 0, stream>>>(stage, bo_u, inv_u, rp_u, pay_u, SHIFT_U, NU, VB_U);

        // m-side: key = movie (edge_from), val = user (edge_to)
        partition_kernel<<<(NE / PEC + 255) / 256, 256, 0, stream>>>(
            edge_from, edge_to, bcur_m, stage, SHIFT_M, NBM, VB_M);
        build_kernel<<<NBM, 256, 0, stream>>>(stage, bo_m, inv_m, rp_m, pay_m, SHIFT_M, NM, VB_M);

        // prescale (stage is dead now; y overlays it)
        prescale_kernel<<<((size_t)NU * DD + 255) / 256, 256, 0, stream>>>(
            emb_user, inv_u, y_u, NU * DD);
        prescale_kernel<<<((size_t)NM * DD + 255) / 256, 256, 0, stream>>>(
            emb_movie, inv_m, y_m, NM * DD);

        gather_kernel<<<((size_t)NU * 64 + 255) / 256, 256, 0, stream>>>(
            rp_u, pay_u, inv_u, y_m, emb_user, res_u, NU);
        gather_kernel<<<((size_t)NM * 64 + 255) / 256, 256, 0, stream>>>(
            rp_m, pay_m, inv_m, y_u, emb_movie, res_m, NM);
    } else {
        // ---- fallback: atomic path ----
        float* fdeg_u = (float*)d_ws;
        float* fdeg_m = fdeg_u + NU;
        hipMemsetAsync(res_u, 0, (size_t)(NU + NM) * DD * sizeof(float), stream);
        hipMemsetAsync(fdeg_u, 0, (size_t)(NU + NM) * sizeof(float), stream);
        degree_kernel_f<<<(NE + 255) / 256, 256, 0, stream>>>(edge_from, edge_to, fdeg_m, fdeg_u);
        inv_kernel_f<<<(NU + NM + 255) / 256, 256, 0, stream>>>(fdeg_u, NU + NM);
        agg_kernel_f<<<((size_t)NE * 64 + 255) / 256, 256, 0, stream>>>(
            edge_from, edge_to, fdeg_m, fdeg_u, emb_user, emb_movie, res_u, res_m);
        add_base_kernel_f<<<((NU + NM) * DD + 255) / 256, 256, 0, stream>>>(
            emb_user, emb_movie, res_u, res_m);
    }

    score_kernel<<<((size_t)NL * 64 + 255) / 256, 256, 0, stream>>>(
        label_movie, label_user, res_u, res_m, scores);
}